// Round 14
// baseline (110.672 us; speedup 1.0000x reference)
//
#include <hip/hip_runtime.h>

// Problem constants
constexpr int IN_C  = 256;
constexpr int MID   = 32;
constexpr int OUT_C = 128;
constexpr int NR    = 512;
constexpr int NL    = 256;
constexpr int M     = 4;
constexpr long ROW_STRIDE = (long)(NR + NL) * OUT_C;   // 768*128 = 98304

// ---- workspace layout ----
// f32 region (float offsets)
constexpr long WS_PR4 = 0;                               // [4][512][32]   (rec proj, slice-major)
constexpr long WS_PL4 = WS_PR4 + 4L * NR * MID;          // [4][4][256][32] (lig proj [s][m][j][y])
constexpr long WS_F32_END = WS_PL4 + 4L * M * NL * MID;  // 196608 floats
// bf16 region (ushort offsets into ws)
constexpr long BF_LRR = 2 * WS_F32_END;                  // [512][32]  r_ri
constexpr long BF_LRL = BF_LRR + (long)NR * MID;         // [512][32]  r_li
constexpr long BF_LLR = BF_LRL + (long)NR * MID;         // [512][32]  r_lj
constexpr long BF_LLL = BF_LLR + (long)NR * MID;         // [256][128] l_li gathered [i][m*32+x]
constexpr long BF_TRR = BF_LLL + (long)NL * M * MID;     // [512][128][32]  T[j][o][k]
constexpr long BF_TRL = BF_TRR + (long)NR * OUT_C * MID; // [256][128][32]
constexpr long BF_TLR = BF_TRL + (long)NL * OUT_C * MID; // [256][128][32]
constexpr long BF_TLL = BF_TLR + (long)NL * OUT_C * MID; // [256][128][128]

typedef __bf16 bf16x8 __attribute__((ext_vector_type(8)));
typedef float  f32x4  __attribute__((ext_vector_type(4)));

__device__ inline unsigned short f2bf(float f) {
    unsigned int u = __float_as_uint(f);
    u = (u + 0x7fffu + ((u >> 16) & 1u)) >> 16;   // round-to-nearest-even
    return (unsigned short)u;
}

union BF8 { unsigned int u[4]; bf16x8 v; };

// ---------------------------------------------------------------------------
// K1: LayerNorm + MFMA projection. 96 blocks x 16 rows. (round-11 version)
// ---------------------------------------------------------------------------
__global__ __launch_bounds__(256) void ln_proj_kernel(
    const float* __restrict__ rec, const float* __restrict__ lig,
    const float* __restrict__ rg, const float* __restrict__ rb,
    const float* __restrict__ lg, const float* __restrict__ lb,
    const float* __restrict__ Wr, const float* __restrict__ br,
    const float* __restrict__ Wl, const float* __restrict__ bl,
    float* __restrict__ ws)
{
    __shared__ unsigned int xn4[16 * 128];     // 16 rows x 128 u32 (bf16 pairs), swizzled
    int bid = blockIdx.x;                      // 0..95; 0-31 rec, 32-95 lig
    int rowbase = bid * 16;
    bool isRec = (rowbase < NR);
    const float* X    = isRec ? rec + (long)rowbase * IN_C
                              : lig + (long)(rowbase - NR) * IN_C;
    const float* g    = isRec ? rg : lg;
    const float* bv   = isRec ? rb : lb;
    const float* W    = isRec ? Wr : Wl;
    const float* bias = isRec ? br : bl;

    int tid = threadIdx.x;
    // ---- LN phase: row rl = tid>>4, 16 lanes per row ----
    {
        int rl = tid >> 4, p = tid & 15;
        const float* xp = X + (long)rl * IN_C + p * 16;
        float4 xv[4];
        float s = 0.f, s2 = 0.f;
        #pragma unroll
        for (int q = 0; q < 4; ++q) {
            xv[q] = *(const float4*)(xp + q * 4);
            s  += xv[q].x + xv[q].y + xv[q].z + xv[q].w;
            s2 += xv[q].x*xv[q].x + xv[q].y*xv[q].y + xv[q].z*xv[q].z + xv[q].w*xv[q].w;
        }
        #pragma unroll
        for (int m = 1; m < 16; m <<= 1) {
            s  += __shfl_xor(s,  m, 64);
            s2 += __shfl_xor(s2, m, 64);
        }
        float mu = s * (1.f / IN_C);
        float var = s2 * (1.f / IN_C) - mu * mu;
        float rs = rsqrtf(var + 1e-5f);
        #pragma unroll
        for (int q = 0; q < 4; ++q) {
            int k0 = p * 16 + q * 4;
            float4 gv = *(const float4*)(g + k0);
            float4 bb = *(const float4*)(bv + k0);
            float n0 = (xv[q].x - mu) * rs * gv.x + bb.x;
            float n1 = (xv[q].y - mu) * rs * gv.y + bb.y;
            float n2 = (xv[q].z - mu) * rs * gv.z + bb.z;
            float n3 = (xv[q].w - mu) * rs * gv.w + bb.w;
            int idx  = rl * 128 + (k0 >> 1);             // even; %4 in {0,2}
            int sidx = idx ^ ((rl & 7) << 2);            // 16B-block XOR swizzle
            xn4[sidx]     = (unsigned)f2bf(n0) | ((unsigned)f2bf(n1) << 16);
            xn4[sidx + 1] = (unsigned)f2bf(n2) | ((unsigned)f2bf(n3) << 16);
        }
    }
    __syncthreads();

    // ---- MFMA projection: wave wv covers outs [wv*32, wv*32+32) ----
    int wv = tid >> 6, l = tid & 63;
    int lrow = l & 15, lk = l >> 4;
    int ob = wv * 32;

    f32x4 acc0 = *(const f32x4*)(bias + ob + lk * 4);        // outs ob+lk*4..+3
    f32x4 acc1 = *(const f32x4*)(bias + ob + 16 + lk * 4);

    for (int ks = 0; ks < 8; ++ks) {
        int idx = (lrow * 128 + ks * 16 + lk * 4) ^ ((lrow & 7) << 2);
        bf16x8 xf = *(const bf16x8*)&xn4[idx];               // B: xn row = lrow
        const float* w0 = W + (long)(ob + lrow) * IN_C + ks * 32 + lk * 8;
        const float* w1 = w0 + 16L * IN_C;
        float4 a0 = *(const float4*)w0, a1 = *(const float4*)(w0 + 4);
        float4 c0 = *(const float4*)w1, c1 = *(const float4*)(w1 + 4);
        BF8 wf0, wf1;
        wf0.u[0] = (unsigned)f2bf(a0.x) | ((unsigned)f2bf(a0.y) << 16);
        wf0.u[1] = (unsigned)f2bf(a0.z) | ((unsigned)f2bf(a0.w) << 16);
        wf0.u[2] = (unsigned)f2bf(a1.x) | ((unsigned)f2bf(a1.y) << 16);
        wf0.u[3] = (unsigned)f2bf(a1.z) | ((unsigned)f2bf(a1.w) << 16);
        wf1.u[0] = (unsigned)f2bf(c0.x) | ((unsigned)f2bf(c0.y) << 16);
        wf1.u[1] = (unsigned)f2bf(c0.z) | ((unsigned)f2bf(c0.w) << 16);
        wf1.u[2] = (unsigned)f2bf(c1.x) | ((unsigned)f2bf(c1.y) << 16);
        wf1.u[3] = (unsigned)f2bf(c1.z) | ((unsigned)f2bf(c1.w) << 16);
        acc0 = __builtin_amdgcn_mfma_f32_16x16x32_bf16(wf0.v, xf, acc0, 0, 0, 0);
        acc1 = __builtin_amdgcn_mfma_f32_16x16x32_bf16(wf1.v, xf, acc1, 0, 0, 0);
    }

    // ---- store: lane row = rowbase+lrow; tile t, reg r -> c = ob + t*16 + lk*4 + r
    unsigned short* wsb = (unsigned short*)ws;
    int prow = isRec ? (rowbase + lrow) : (rowbase - NR + lrow);
    long slice_stride = isRec ? (long)NR * MID : (long)M * NL * MID;
    float* P4 = isRec ? (ws + WS_PR4) : (ws + WS_PL4);
    #pragma unroll
    for (int t = 0; t < 2; ++t) {
        f32x4 acc = t ? acc1 : acc0;
        int xi = (ob >> 2) + t * 4 + lk;
        #pragma unroll
        for (int r = 0; r < 4; ++r) {
            float val = acc[r];
            P4[(long)r * slice_stride + (long)prow * MID + xi] = val;
            unsigned short hb = f2bf(val);
            if (isRec) {
                if (r == 0)      wsb[BF_LRR + (long)prow * 32 + xi] = hb;
                else if (r == 2) wsb[BF_LRL + (long)prow * 32 + xi] = hb;
                else if (r == 3) wsb[BF_LLR + (long)prow * 32 + xi] = hb;
            } else if (r == 2) { // l_li -> LLL[j][m*32+xi], prow = m*256+j
                wsb[BF_LLL + (long)(prow & 255) * 128 + (prow >> 8) * 32 + xi] = hb;
            }
        }
    }
}

// ---------------------------------------------------------------------------
// K3 (MFMA version, round-13 proven): T[c][v] = W[c][y] . V[v][y], K=32.
// ---------------------------------------------------------------------------
__global__ __launch_bounds__(256) void build_t_kernel(
    const float* __restrict__ Wrr, const float* __restrict__ Wrl,
    const float* __restrict__ Wlr, const float* __restrict__ Wll,
    float* __restrict__ ws)
{
    __shared__ unsigned int Vs[512 * 16];   // bf16 pairs, 16B-block XOR swizzle
    __shared__ unsigned int Wsh[64 * 16];
    unsigned short* wsb = (unsigned short*)ws;
    const float* V4 = ws + WS_PL4;          // [s][m][j][y]
    int bid = blockIdx.x;
    int tid = threadIdx.x;

    int mode, cblk, jhalf = 0, Vrows;
    const float* W;
    unsigned short* T;
    if (bid < 64)       { mode = 0; cblk = bid;       W = Wrr; T = wsb + BF_TRR; Vrows = 512; }
    else if (bid < 128) { mode = 1; cblk = bid - 64;  W = Wrl; T = wsb + BF_TRL; Vrows = 256; }
    else if (bid < 192) { mode = 2; cblk = bid - 128; W = Wlr; T = wsb + BF_TLR; Vrows = 256; }
    else                { mode = 3; int r = bid - 192; cblk = r >> 1; jhalf = r & 1;
                          W = Wll; T = wsb + BF_TLL; Vrows = 512; }

    // ---- stage V (f32 -> bf16 pairs, swizzled). 8 y-values per thread-iter.
    for (int f = tid; f < Vrows * 4; f += 256) {
        int row = f >> 2, blk = f & 3;
        int y0 = blk * 8;
        float vals[8];
        if (mode == 0) {
            const float* p = ws + WS_PR4 + (long)NR * MID + (long)row * 32 + y0;  // r_rj
            #pragma unroll
            for (int i = 0; i < 8; ++i) vals[i] = p[i];
        } else if (mode == 3) {
            const float* p = V4 + 3L * M * NL * MID + (long)(jhalf * 512 + row) * 32 + y0; // l_lj
            #pragma unroll
            for (int i = 0; i < 8; ++i) vals[i] = 0.25f * p[i];                   // fold /m
        } else {
            int sl = (mode == 1) ? 1 : 0;                                         // l_rj / l_ri
            const float* p = V4 + (long)sl * M * NL * MID + (long)row * 32 + y0;
            #pragma unroll
            for (int i = 0; i < 8; ++i)
                vals[i] = 0.25f * (p[i] + p[8192 + i] + p[16384 + i] + p[24576 + i]);
        }
        unsigned int* dst = &Vs[row * 16 + ((blk ^ (row & 3)) << 2)];
        #pragma unroll
        for (int q = 0; q < 4; ++q)
            dst[q] = (unsigned)f2bf(vals[2*q]) | ((unsigned)f2bf(vals[2*q+1]) << 16);
    }
    // ---- stage W chunk: 64 rows x 32 y (one iter: tid>>2 = row, tid&3 = blk)
    {
        int row = tid >> 2, blk = tid & 3;
        const float* p = W + (long)(cblk * 64 + row) * 32 + blk * 8;
        float4 a = *(const float4*)p, b = *(const float4*)(p + 4);
        unsigned int* dst = &Wsh[row * 16 + ((blk ^ (row & 3)) << 2)];
        dst[0] = (unsigned)f2bf(a.x) | ((unsigned)f2bf(a.y) << 16);
        dst[1] = (unsigned)f2bf(a.z) | ((unsigned)f2bf(a.w) << 16);
        dst[2] = (unsigned)f2bf(b.x) | ((unsigned)f2bf(b.y) << 16);
        dst[3] = (unsigned)f2bf(b.z) | ((unsigned)f2bf(b.w) << 16);
    }
    __syncthreads();

    int wv = tid >> 6, l = tid & 63;
    int lrow = l & 15, lk = l >> 4;
    int wrow = wv * 16 + lrow;
    bf16x8 af = *(const bf16x8*)&Wsh[wrow * 16 + ((lk ^ (wrow & 3)) << 2)];
    int c0 = cblk * 64 + wv * 16 + lk * 4;

    int nj = Vrows >> 4;
    for (int jt = 0; jt < nj; ++jt) {
        int vr = jt * 16 + lrow;
        bf16x8 bf = *(const bf16x8*)&Vs[vr * 16 + ((lk ^ (vr & 3)) << 2)];
        f32x4 acc = {0.f, 0.f, 0.f, 0.f};
        acc = __builtin_amdgcn_mfma_f32_16x16x32_bf16(af, bf, acc, 0, 0, 0);
        unsigned long long pk =
              (unsigned long long)f2bf(acc[0])
            | ((unsigned long long)f2bf(acc[1]) << 16)
            | ((unsigned long long)f2bf(acc[2]) << 32)
            | ((unsigned long long)f2bf(acc[3]) << 48);
        if (mode < 3) {
            *(unsigned long long*)(T + (long)vr * 4096 + c0) = pk;
        } else {
            int vg = jhalf * 512 + vr;
            int m = vg >> 8, j = vg & 255;
            *(unsigned long long*)(T + (long)j * 16384 + ((c0 >> 5) << 7) + m * 32 + (c0 & 31)) = pk;
        }
    }
}

// ---------------------------------------------------------------------------
// K4 (j-sweep version): block = 16 i rows x long j window; wave wv handles
// j === wv (mod 4) in a tight {8x load+mfma+store} loop. Per i-row the store
// stream is a 16-64 KB MONOTONIC sequential run (vs max 2 KB before) while
// adjacent-j simultaneity across waves is preserved -> DRAM row-buffer
// friendly. lr keeps the round-7 structure (already dense per wave-step).
// Grid 1024 = 8 XCDs x (32 rr + 32 rl + 32 lr + 32 ll), compute-balanced.
// ---------------------------------------------------------------------------
template<int K, int JB>
__device__ inline void epi_sweep(
    const unsigned short* __restrict__ L,
    const unsigned short* __restrict__ T0,   // Tq + j0*K*128
    const float* __restrict__ bias,
    float* __restrict__ ob,                  // quadrant base + j0*128
    int i0, int lrow, int lk, int wv)
{
    constexpr int NK = K / 32;
    bf16x8 bl[NK];
    #pragma unroll
    for (int ks = 0; ks < NK; ++ks)
        bl[ks] = *(const bf16x8*)(L + (long)(i0 + lrow) * K + ks * 32 + lk * 8);
    f32x4 b4[8];
    #pragma unroll
    for (int of = 0; of < 8; ++of)
        b4[of] = *(const f32x4*)(bias + of * 16 + lk * 4);
    float* orow = ob + (long)(i0 + lrow) * ROW_STRIDE + lk * 4;
    for (int s = 0; s < JB / 4; ++s) {
        int j = s * 4 + wv;
        const unsigned short* T = T0 + (long)j * (K * 128);
        float* oj = orow + (long)j * 128;
        #pragma unroll
        for (int of = 0; of < 8; ++of) {
            f32x4 acc = b4[of];
            #pragma unroll
            for (int ks = 0; ks < NK; ++ks) {
                bf16x8 a = *(const bf16x8*)(T + (long)(of * 16 + lrow) * K + ks * 32 + lk * 8);
                acc = __builtin_amdgcn_mfma_f32_16x16x32_bf16(a, bl[ks], acc, 0, 0, 0);
            }
            *(f32x4*)(oj + of * 16) = acc;
        }
    }
}

// round-7 epi_wave, used for the lr quadrant (dense store pattern there).
template<int K>
__device__ inline void epi_wave(const unsigned short* __restrict__ L,
                                const unsigned short* __restrict__ T,
                                const float* __restrict__ bias,
                                float* __restrict__ obrow,
                                long istr, int i0, int lrow, int lk)
{
    constexpr int NK = K / 32;
    bf16x8 bl0[NK], bl1[NK];
    #pragma unroll
    for (int ks = 0; ks < NK; ++ks) {
        int kb = ks * 32 + lk * 8;
        bl0[ks] = *(const bf16x8*)(L + (long)(i0 + lrow) * K + kb);
        bl1[ks] = *(const bf16x8*)(L + (long)(i0 + 16 + lrow) * K + kb);
    }
    f32x4 acc[2][8];
    #pragma unroll
    for (int of = 0; of < 8; ++of) {
        f32x4 b4 = *(const f32x4*)(bias + of * 16 + lk * 4);
        acc[0][of] = b4; acc[1][of] = b4;
    }
    #pragma unroll
    for (int ks = 0; ks < NK; ++ks) {
        int kb = ks * 32 + lk * 8;
        #pragma unroll
        for (int of = 0; of < 8; ++of) {
            bf16x8 a = *(const bf16x8*)(T + (long)(of * 16 + lrow) * K + kb);
            acc[0][of] = __builtin_amdgcn_mfma_f32_16x16x32_bf16(a, bl0[ks], acc[0][of], 0, 0, 0);
            acc[1][of] = __builtin_amdgcn_mfma_f32_16x16x32_bf16(a, bl1[ks], acc[1][of], 0, 0, 0);
        }
    }
    float* obase = obrow + (long)lk * 4;
    #pragma unroll
    for (int fi = 0; fi < 2; ++fi) {
        long ibase = (long)(i0 + fi * 16 + lrow) * istr;
        #pragma unroll
        for (int of = 0; of < 8; ++of) {
            *(f32x4*)(obase + ibase + of * 16) = acc[fi][of];
        }
    }
}

__global__ __launch_bounds__(256) void epilogue_kernel(
    const float* __restrict__ ws, float* __restrict__ out,
    const float* __restrict__ brr, const float* __restrict__ brl,
    const float* __restrict__ blr, const float* __restrict__ bll)
{
    const unsigned short* wsb = (const unsigned short*)ws;
    int bid = blockIdx.x;
    int x = bid & 7;      // XCD (dispatch round-robin heuristic; perf-only)
    int r = bid >> 3;     // 0..127 within XCD

    int tid = threadIdx.x;
    int wv = tid >> 6, l = tid & 63;
    int lrow = l & 15, lk = l >> 4;

    if (r < 32) {               // rr: 16i x 64j sweep, K=32
        int i0 = r * 16, j0 = x * 64;
        epi_sweep<32, 64>(wsb + BF_LRR, wsb + BF_TRR + (long)j0 * 4096, brr,
                          out + (long)j0 * 128, i0, lrow, lk, wv);
    } else if (r < 64) {        // rl: 16i x 32j sweep, K=32
        int i0 = (r - 32) * 16, j0 = x * 32;
        epi_sweep<32, 32>(wsb + BF_LRL, wsb + BF_TRL + (long)j0 * 4096, brl,
                          out + (long)NR * OUT_C + (long)j0 * 128, i0, lrow, lk, wv);
    } else if (r < 96) {        // lr: round-7 structure, block 64i x 8j
        int w = r - 64; int it = w & 7, jw = w >> 3;
        int j0 = x * 32 + jw * 8, i0b = it * 64;
        const unsigned short* L = wsb + BF_LLR;
        float* ob = out + (long)NR * ROW_STRIDE;
        #pragma unroll
        for (int jj = 0; jj < 2; ++jj) {
            int j = j0 + jj * 4 + wv;
            const unsigned short* T = wsb + BF_TLR + (long)j * 4096;
            float* obj = ob + (long)j * ROW_STRIDE;
            #pragma unroll
            for (int ic = 0; ic < 2; ++ic)
                epi_wave<32>(L, T, blr, obj, 128, i0b + ic * 32, lrow, lk);
        }
    } else {                    // ll: 16i x 16j sweep, K=128
        int w = r - 96; int it = w & 15, jw = w >> 4;
        int i0 = it * 16, j0 = x * 32 + jw * 16;
        epi_sweep<128, 16>(wsb + BF_LLL, wsb + BF_TLL + (long)j0 * 16384, bll,
                           out + (long)NR * ROW_STRIDE + (long)NR * OUT_C + (long)j0 * 128,
                           i0, lrow, lk, wv);
    }
}

extern "C" void kernel_launch(void* const* d_in, const int* in_sizes, int n_in,
                              void* d_out, int out_size, void* d_ws, size_t ws_size,
                              hipStream_t stream)
{
    (void)in_sizes; (void)n_in; (void)out_size; (void)ws_size;
    const float* rec = (const float*)d_in[0];
    const float* lig = (const float*)d_in[1];
    // d_in[2] = pw_rep: shape-only, never read (all 4 quadrants are overwritten)
    const float* rg  = (const float*)d_in[3];
    const float* rb  = (const float*)d_in[4];
    const float* lg  = (const float*)d_in[5];
    const float* lb  = (const float*)d_in[6];
    const float* Wr  = (const float*)d_in[7];
    const float* br  = (const float*)d_in[8];
    const float* Wl  = (const float*)d_in[9];
    const float* bl  = (const float*)d_in[10];
    const float* Wrr = (const float*)d_in[11];
    const float* brr = (const float*)d_in[12];
    const float* Wrl = (const float*)d_in[13];
    const float* brl = (const float*)d_in[14];
    const float* Wlr = (const float*)d_in[15];
    const float* blr = (const float*)d_in[16];
    const float* Wll = (const float*)d_in[17];
    const float* bll = (const float*)d_in[18];
    float* out = (float*)d_out;
    float* ws  = (float*)d_ws;

    hipLaunchKernelGGL(ln_proj_kernel, dim3(96), dim3(256), 0, stream,
                       rec, lig, rg, rb, lg, lb, Wr, br, Wl, bl, ws);
    hipLaunchKernelGGL(build_t_kernel, dim3(320), dim3(256), 0, stream,
                       Wrr, Wrl, Wlr, Wll, ws);
    hipLaunchKernelGGL(epilogue_kernel, dim3(1024), dim3(256), 0, stream,
                       ws, out, brr, brl, blr, bll);
}

// Round 15
// 96.403 us; speedup vs baseline: 1.1480x; 1.1480x over previous
//
#include <hip/hip_runtime.h>

// Problem constants
constexpr int IN_C  = 256;
constexpr int MID   = 32;
constexpr int OUT_C = 128;
constexpr int NR    = 512;
constexpr int NL    = 256;
constexpr int M     = 4;
constexpr long ROW_STRIDE = (long)(NR + NL) * OUT_C;   // 768*128 = 98304

// ---- workspace layout ----
// f32 region (float offsets)
constexpr long WS_PR4 = 0;                               // [4][512][32]   (rec proj, slice-major)
constexpr long WS_PL4 = WS_PR4 + 4L * NR * MID;          // [4][4][256][32] (lig proj [s][m][j][y])
constexpr long WS_F32_END = WS_PL4 + 4L * M * NL * MID;  // 196608 floats
// bf16 region (ushort offsets into ws)
constexpr long BF_LRR = 2 * WS_F32_END;                  // [512][32]  r_ri
constexpr long BF_LRL = BF_LRR + (long)NR * MID;         // [512][32]  r_li
constexpr long BF_LLR = BF_LRL + (long)NR * MID;         // [512][32]  r_lj
constexpr long BF_LLL = BF_LLR + (long)NR * MID;         // [256][128] l_li gathered [i][m*32+x]
constexpr long BF_TRR = BF_LLL + (long)NL * M * MID;     // [512][128][32]  T[j][o][k]
constexpr long BF_TRL = BF_TRR + (long)NR * OUT_C * MID; // [256][128][32]
constexpr long BF_TLR = BF_TRL + (long)NL * OUT_C * MID; // [256][128][32]
constexpr long BF_TLL = BF_TLR + (long)NL * OUT_C * MID; // [256][128][128]

typedef __bf16 bf16x8 __attribute__((ext_vector_type(8)));
typedef float  f32x4  __attribute__((ext_vector_type(4)));

__device__ inline unsigned short f2bf(float f) {
    unsigned int u = __float_as_uint(f);
    u = (u + 0x7fffu + ((u >> 16) & 1u)) >> 16;   // round-to-nearest-even
    return (unsigned short)u;
}

union BF8 { unsigned int u[4]; bf16x8 v; };

// ---------------------------------------------------------------------------
// K1: LayerNorm + MFMA projection. 96 blocks x 16 rows. (round-11 version)
// ---------------------------------------------------------------------------
__global__ __launch_bounds__(256) void ln_proj_kernel(
    const float* __restrict__ rec, const float* __restrict__ lig,
    const float* __restrict__ rg, const float* __restrict__ rb,
    const float* __restrict__ lg, const float* __restrict__ lb,
    const float* __restrict__ Wr, const float* __restrict__ br,
    const float* __restrict__ Wl, const float* __restrict__ bl,
    float* __restrict__ ws)
{
    __shared__ unsigned int xn4[16 * 128];     // 16 rows x 128 u32 (bf16 pairs), swizzled
    int bid = blockIdx.x;                      // 0..95; 0-31 rec, 32-95 lig
    int rowbase = bid * 16;
    bool isRec = (rowbase < NR);
    const float* X    = isRec ? rec + (long)rowbase * IN_C
                              : lig + (long)(rowbase - NR) * IN_C;
    const float* g    = isRec ? rg : lg;
    const float* bv   = isRec ? rb : lb;
    const float* W    = isRec ? Wr : Wl;
    const float* bias = isRec ? br : bl;

    int tid = threadIdx.x;
    // ---- LN phase: row rl = tid>>4, 16 lanes per row ----
    {
        int rl = tid >> 4, p = tid & 15;
        const float* xp = X + (long)rl * IN_C + p * 16;
        float4 xv[4];
        float s = 0.f, s2 = 0.f;
        #pragma unroll
        for (int q = 0; q < 4; ++q) {
            xv[q] = *(const float4*)(xp + q * 4);
            s  += xv[q].x + xv[q].y + xv[q].z + xv[q].w;
            s2 += xv[q].x*xv[q].x + xv[q].y*xv[q].y + xv[q].z*xv[q].z + xv[q].w*xv[q].w;
        }
        #pragma unroll
        for (int m = 1; m < 16; m <<= 1) {
            s  += __shfl_xor(s,  m, 64);
            s2 += __shfl_xor(s2, m, 64);
        }
        float mu = s * (1.f / IN_C);
        float var = s2 * (1.f / IN_C) - mu * mu;
        float rs = rsqrtf(var + 1e-5f);
        #pragma unroll
        for (int q = 0; q < 4; ++q) {
            int k0 = p * 16 + q * 4;
            float4 gv = *(const float4*)(g + k0);
            float4 bb = *(const float4*)(bv + k0);
            float n0 = (xv[q].x - mu) * rs * gv.x + bb.x;
            float n1 = (xv[q].y - mu) * rs * gv.y + bb.y;
            float n2 = (xv[q].z - mu) * rs * gv.z + bb.z;
            float n3 = (xv[q].w - mu) * rs * gv.w + bb.w;
            int idx  = rl * 128 + (k0 >> 1);             // even; %4 in {0,2}
            int sidx = idx ^ ((rl & 7) << 2);            // 16B-block XOR swizzle
            xn4[sidx]     = (unsigned)f2bf(n0) | ((unsigned)f2bf(n1) << 16);
            xn4[sidx + 1] = (unsigned)f2bf(n2) | ((unsigned)f2bf(n3) << 16);
        }
    }
    __syncthreads();

    // ---- MFMA projection: wave wv covers outs [wv*32, wv*32+32) ----
    int wv = tid >> 6, l = tid & 63;
    int lrow = l & 15, lk = l >> 4;
    int ob = wv * 32;

    f32x4 acc0 = *(const f32x4*)(bias + ob + lk * 4);        // outs ob+lk*4..+3
    f32x4 acc1 = *(const f32x4*)(bias + ob + 16 + lk * 4);

    for (int ks = 0; ks < 8; ++ks) {
        int idx = (lrow * 128 + ks * 16 + lk * 4) ^ ((lrow & 7) << 2);
        bf16x8 xf = *(const bf16x8*)&xn4[idx];               // B: xn row = lrow
        const float* w0 = W + (long)(ob + lrow) * IN_C + ks * 32 + lk * 8;
        const float* w1 = w0 + 16L * IN_C;
        float4 a0 = *(const float4*)w0, a1 = *(const float4*)(w0 + 4);
        float4 c0 = *(const float4*)w1, c1 = *(const float4*)(w1 + 4);
        BF8 wf0, wf1;
        wf0.u[0] = (unsigned)f2bf(a0.x) | ((unsigned)f2bf(a0.y) << 16);
        wf0.u[1] = (unsigned)f2bf(a0.z) | ((unsigned)f2bf(a0.w) << 16);
        wf0.u[2] = (unsigned)f2bf(a1.x) | ((unsigned)f2bf(a1.y) << 16);
        wf0.u[3] = (unsigned)f2bf(a1.z) | ((unsigned)f2bf(a1.w) << 16);
        wf1.u[0] = (unsigned)f2bf(c0.x) | ((unsigned)f2bf(c0.y) << 16);
        wf1.u[1] = (unsigned)f2bf(c0.z) | ((unsigned)f2bf(c0.w) << 16);
        wf1.u[2] = (unsigned)f2bf(c1.x) | ((unsigned)f2bf(c1.y) << 16);
        wf1.u[3] = (unsigned)f2bf(c1.z) | ((unsigned)f2bf(c1.w) << 16);
        acc0 = __builtin_amdgcn_mfma_f32_16x16x32_bf16(wf0.v, xf, acc0, 0, 0, 0);
        acc1 = __builtin_amdgcn_mfma_f32_16x16x32_bf16(wf1.v, xf, acc1, 0, 0, 0);
    }

    // ---- store: lane row = rowbase+lrow; tile t, reg r -> c = ob + t*16 + lk*4 + r
    unsigned short* wsb = (unsigned short*)ws;
    int prow = isRec ? (rowbase + lrow) : (rowbase - NR + lrow);
    long slice_stride = isRec ? (long)NR * MID : (long)M * NL * MID;
    float* P4 = isRec ? (ws + WS_PR4) : (ws + WS_PL4);
    #pragma unroll
    for (int t = 0; t < 2; ++t) {
        f32x4 acc = t ? acc1 : acc0;
        int xi = (ob >> 2) + t * 4 + lk;
        #pragma unroll
        for (int r = 0; r < 4; ++r) {
            float val = acc[r];
            P4[(long)r * slice_stride + (long)prow * MID + xi] = val;
            unsigned short hb = f2bf(val);
            if (isRec) {
                if (r == 0)      wsb[BF_LRR + (long)prow * 32 + xi] = hb;
                else if (r == 2) wsb[BF_LRL + (long)prow * 32 + xi] = hb;
                else if (r == 3) wsb[BF_LLR + (long)prow * 32 + xi] = hb;
            } else if (r == 2) { // l_li -> LLL[j][m*32+xi], prow = m*256+j
                wsb[BF_LLL + (long)(prow & 255) * 128 + (prow >> 8) * 32 + xi] = hb;
            }
        }
    }
}

// ---------------------------------------------------------------------------
// K3 (MFMA version, round-13 proven): T[c][v] = W[c][y] . V[v][y], K=32.
// ---------------------------------------------------------------------------
__global__ __launch_bounds__(256) void build_t_kernel(
    const float* __restrict__ Wrr, const float* __restrict__ Wrl,
    const float* __restrict__ Wlr, const float* __restrict__ Wll,
    float* __restrict__ ws)
{
    __shared__ unsigned int Vs[512 * 16];   // bf16 pairs, 16B-block XOR swizzle
    __shared__ unsigned int Wsh[64 * 16];
    unsigned short* wsb = (unsigned short*)ws;
    const float* V4 = ws + WS_PL4;          // [s][m][j][y]
    int bid = blockIdx.x;
    int tid = threadIdx.x;

    int mode, cblk, jhalf = 0, Vrows;
    const float* W;
    unsigned short* T;
    if (bid < 64)       { mode = 0; cblk = bid;       W = Wrr; T = wsb + BF_TRR; Vrows = 512; }
    else if (bid < 128) { mode = 1; cblk = bid - 64;  W = Wrl; T = wsb + BF_TRL; Vrows = 256; }
    else if (bid < 192) { mode = 2; cblk = bid - 128; W = Wlr; T = wsb + BF_TLR; Vrows = 256; }
    else                { mode = 3; int r = bid - 192; cblk = r >> 1; jhalf = r & 1;
                          W = Wll; T = wsb + BF_TLL; Vrows = 512; }

    // ---- stage V (f32 -> bf16 pairs, swizzled). 8 y-values per thread-iter.
    for (int f = tid; f < Vrows * 4; f += 256) {
        int row = f >> 2, blk = f & 3;
        int y0 = blk * 8;
        float vals[8];
        if (mode == 0) {
            const float* p = ws + WS_PR4 + (long)NR * MID + (long)row * 32 + y0;  // r_rj
            #pragma unroll
            for (int i = 0; i < 8; ++i) vals[i] = p[i];
        } else if (mode == 3) {
            const float* p = V4 + 3L * M * NL * MID + (long)(jhalf * 512 + row) * 32 + y0; // l_lj
            #pragma unroll
            for (int i = 0; i < 8; ++i) vals[i] = 0.25f * p[i];                   // fold /m
        } else {
            int sl = (mode == 1) ? 1 : 0;                                         // l_rj / l_ri
            const float* p = V4 + (long)sl * M * NL * MID + (long)row * 32 + y0;
            #pragma unroll
            for (int i = 0; i < 8; ++i)
                vals[i] = 0.25f * (p[i] + p[8192 + i] + p[16384 + i] + p[24576 + i]);
        }
        unsigned int* dst = &Vs[row * 16 + ((blk ^ (row & 3)) << 2)];
        #pragma unroll
        for (int q = 0; q < 4; ++q)
            dst[q] = (unsigned)f2bf(vals[2*q]) | ((unsigned)f2bf(vals[2*q+1]) << 16);
    }
    // ---- stage W chunk: 64 rows x 32 y (one iter: tid>>2 = row, tid&3 = blk)
    {
        int row = tid >> 2, blk = tid & 3;
        const float* p = W + (long)(cblk * 64 + row) * 32 + blk * 8;
        float4 a = *(const float4*)p, b = *(const float4*)(p + 4);
        unsigned int* dst = &Wsh[row * 16 + ((blk ^ (row & 3)) << 2)];
        dst[0] = (unsigned)f2bf(a.x) | ((unsigned)f2bf(a.y) << 16);
        dst[1] = (unsigned)f2bf(a.z) | ((unsigned)f2bf(a.w) << 16);
        dst[2] = (unsigned)f2bf(b.x) | ((unsigned)f2bf(b.y) << 16);
        dst[3] = (unsigned)f2bf(b.z) | ((unsigned)f2bf(b.w) << 16);
    }
    __syncthreads();

    int wv = tid >> 6, l = tid & 63;
    int lrow = l & 15, lk = l >> 4;
    int wrow = wv * 16 + lrow;
    bf16x8 af = *(const bf16x8*)&Wsh[wrow * 16 + ((lk ^ (wrow & 3)) << 2)];
    int c0 = cblk * 64 + wv * 16 + lk * 4;

    int nj = Vrows >> 4;
    for (int jt = 0; jt < nj; ++jt) {
        int vr = jt * 16 + lrow;
        bf16x8 bf = *(const bf16x8*)&Vs[vr * 16 + ((lk ^ (vr & 3)) << 2)];
        f32x4 acc = {0.f, 0.f, 0.f, 0.f};
        acc = __builtin_amdgcn_mfma_f32_16x16x32_bf16(af, bf, acc, 0, 0, 0);
        unsigned long long pk =
              (unsigned long long)f2bf(acc[0])
            | ((unsigned long long)f2bf(acc[1]) << 16)
            | ((unsigned long long)f2bf(acc[2]) << 32)
            | ((unsigned long long)f2bf(acc[3]) << 48);
        if (mode < 3) {
            *(unsigned long long*)(T + (long)vr * 4096 + c0) = pk;
        } else {
            int vg = jhalf * 512 + vr;
            int m = vg >> 8, j = vg & 255;
            *(unsigned long long*)(T + (long)j * 16384 + ((c0 >> 5) << 7) + m * 32 + (c0 & 31)) = pk;
        }
    }
}

// ---------------------------------------------------------------------------
// K4: MFMA epilogue, wave-per-j, i-tile 128 (ic loops 4 x 32 i).
// Same structure as round-7/13 proven version; only the i-tile doubled to
// HALVE cross-block T re-reads (rr/rl 8->4, lr 8->4, ll 2->... ~96->~48 MB).
// Grid 1152 = 8 XCDs x (64 rr + 32 rl + 32 lr + 16 ll), jw-fastest.
// ---------------------------------------------------------------------------
template<int K>
__device__ inline void epi_wave(const unsigned short* __restrict__ L,
                                const unsigned short* __restrict__ T,
                                const float* __restrict__ bias,
                                float* __restrict__ obrow,
                                long istr, int i0, int lrow, int lk)
{
    constexpr int NK = K / 32;
    bf16x8 bl0[NK], bl1[NK];
    #pragma unroll
    for (int ks = 0; ks < NK; ++ks) {
        int kb = ks * 32 + lk * 8;
        bl0[ks] = *(const bf16x8*)(L + (long)(i0 + lrow) * K + kb);
        bl1[ks] = *(const bf16x8*)(L + (long)(i0 + 16 + lrow) * K + kb);
    }
    f32x4 acc[2][8];
    #pragma unroll
    for (int of = 0; of < 8; ++of) {
        f32x4 b4 = *(const f32x4*)(bias + of * 16 + lk * 4);
        acc[0][of] = b4; acc[1][of] = b4;
    }
    #pragma unroll
    for (int ks = 0; ks < NK; ++ks) {
        int kb = ks * 32 + lk * 8;
        #pragma unroll
        for (int of = 0; of < 8; ++of) {
            bf16x8 a = *(const bf16x8*)(T + (long)(of * 16 + lrow) * K + kb);
            acc[0][of] = __builtin_amdgcn_mfma_f32_16x16x32_bf16(a, bl0[ks], acc[0][of], 0, 0, 0);
            acc[1][of] = __builtin_amdgcn_mfma_f32_16x16x32_bf16(a, bl1[ks], acc[1][of], 0, 0, 0);
        }
    }
    float* obase = obrow + (long)lk * 4;
    #pragma unroll
    for (int fi = 0; fi < 2; ++fi) {
        long ibase = (long)(i0 + fi * 16 + lrow) * istr;
        #pragma unroll
        for (int of = 0; of < 8; ++of) {
            *(f32x4*)(obase + ibase + of * 16) = acc[fi][of];
        }
    }
}

__global__ __launch_bounds__(256) void epilogue_kernel(
    const float* __restrict__ ws, float* __restrict__ out,
    const float* __restrict__ brr, const float* __restrict__ brl,
    const float* __restrict__ blr, const float* __restrict__ bll)
{
    const unsigned short* wsb = (const unsigned short*)ws;
    int bid = blockIdx.x;
    int x = bid & 7;      // XCD (dispatch round-robin heuristic; perf-only)
    int r = bid >> 3;     // 0..143 within XCD

    const unsigned short *L, *Tq;
    const float* bias;
    float* ob;
    long istr, jstr;
    int j0, i0b, quadK;
    if (r < 64) {                // rr: 4 it x 16 jw (4 j each), j window 64/XCD
        int jw = r & 15, it = r >> 4;
        j0 = x * 64 + jw * 4; i0b = it * 128; quadK = 32;
        L = wsb + BF_LRR; Tq = wsb + BF_TRR; bias = brr;
        ob = out; jstr = 128; istr = ROW_STRIDE;
    } else if (r < 96) {         // rl: 4 it x 8 jw, j window 32/XCD
        int w = r - 64; int jw = w & 7, it = w >> 3;
        j0 = x * 32 + jw * 4; i0b = it * 128; quadK = 32;
        L = wsb + BF_LRL; Tq = wsb + BF_TRL; bias = brl;
        ob = out + (long)NR * OUT_C; jstr = 128; istr = ROW_STRIDE;
    } else if (r < 128) {        // lr: rows NR+j (lig), cols i (rec); 4 it x 8 jw
        int w = r - 96; int jw = w & 7, it = w >> 3;
        j0 = x * 32 + jw * 4; i0b = it * 128; quadK = 32;
        L = wsb + BF_LLR; Tq = wsb + BF_TLR; bias = blr;
        ob = out + (long)NR * ROW_STRIDE; jstr = ROW_STRIDE; istr = 128;
    } else {                     // ll: 2 it x 8 jw, K=128
        int w = r - 128; int jw = w & 7, it = w >> 3;
        j0 = x * 32 + jw * 4; i0b = it * 128; quadK = 128;
        L = wsb + BF_LLL; Tq = wsb + BF_TLL; bias = bll;
        ob = out + (long)NR * ROW_STRIDE + (long)NR * OUT_C; jstr = 128; istr = ROW_STRIDE;
    }

    int tid = threadIdx.x;
    int wv = tid >> 6, l = tid & 63;
    int lrow = l & 15, lk = l >> 4;
    int j = j0 + wv;

    if (quadK == 32) {
        const unsigned short* T = Tq + (long)j * 4096;
        float* obj = ob + (long)j * jstr;
        #pragma unroll
        for (int ic = 0; ic < 4; ++ic)
            epi_wave<32>(L, T, bias, obj, istr, i0b + ic * 32, lrow, lk);
    } else {
        const unsigned short* T = Tq + (long)j * 16384;
        float* obj = ob + (long)j * jstr;
        #pragma unroll
        for (int ic = 0; ic < 4; ++ic)
            epi_wave<128>(L, T, bias, obj, istr, i0b + ic * 32, lrow, lk);
    }
}

extern "C" void kernel_launch(void* const* d_in, const int* in_sizes, int n_in,
                              void* d_out, int out_size, void* d_ws, size_t ws_size,
                              hipStream_t stream)
{
    (void)in_sizes; (void)n_in; (void)out_size; (void)ws_size;
    const float* rec = (const float*)d_in[0];
    const float* lig = (const float*)d_in[1];
    // d_in[2] = pw_rep: shape-only, never read (all 4 quadrants are overwritten)
    const float* rg  = (const float*)d_in[3];
    const float* rb  = (const float*)d_in[4];
    const float* lg  = (const float*)d_in[5];
    const float* lb  = (const float*)d_in[6];
    const float* Wr  = (const float*)d_in[7];
    const float* br  = (const float*)d_in[8];
    const float* Wl  = (const float*)d_in[9];
    const float* bl  = (const float*)d_in[10];
    const float* Wrr = (const float*)d_in[11];
    const float* brr = (const float*)d_in[12];
    const float* Wrl = (const float*)d_in[13];
    const float* brl = (const float*)d_in[14];
    const float* Wlr = (const float*)d_in[15];
    const float* blr = (const float*)d_in[16];
    const float* Wll = (const float*)d_in[17];
    const float* bll = (const float*)d_in[18];
    float* out = (float*)d_out;
    float* ws  = (float*)d_ws;

    hipLaunchKernelGGL(ln_proj_kernel, dim3(96), dim3(256), 0, stream,
                       rec, lig, rg, rb, lg, lb, Wr, br, Wl, bl, ws);
    hipLaunchKernelGGL(build_t_kernel, dim3(320), dim3(256), 0, stream,
                       Wrr, Wrl, Wlr, Wll, ws);
    hipLaunchKernelGGL(epilogue_kernel, dim3(1152), dim3(256), 0, stream,
                       ws, out, brr, brl, blr, bll);
}

// Round 16
// 85.689 us; speedup vs baseline: 1.2916x; 1.1250x over previous
//
#include <hip/hip_runtime.h>

// Problem constants
constexpr int IN_C  = 256;
constexpr int MID   = 32;
constexpr int OUT_C = 128;
constexpr int NR    = 512;
constexpr int NL    = 256;
constexpr int M     = 4;
constexpr long ROW_STRIDE = (long)(NR + NL) * OUT_C;   // 768*128 = 98304

// ---- workspace layout ----
// f32 region (float offsets)
constexpr long WS_PR4 = 0;                               // [4][512][32]   (rec proj, slice-major)
constexpr long WS_PL4 = WS_PR4 + 4L * NR * MID;          // [4][4][256][32] (lig proj [s][m][j][y])
constexpr long WS_F32_END = WS_PL4 + 4L * M * NL * MID;  // 196608 floats
// bf16 region (ushort offsets into ws)
constexpr long BF_LRR = 2 * WS_F32_END;                  // [512][32]  r_ri
constexpr long BF_LRL = BF_LRR + (long)NR * MID;         // [512][32]  r_li
constexpr long BF_LLR = BF_LRL + (long)NR * MID;         // [512][32]  r_lj
constexpr long BF_LLL = BF_LLR + (long)NR * MID;         // [256][128] l_li gathered [i][m*32+x]
constexpr long BF_TRR = BF_LLL + (long)NL * M * MID;     // [512][128][32]  T[j][o][k]
constexpr long BF_TRL = BF_TRR + (long)NR * OUT_C * MID; // [256][128][32]
constexpr long BF_TLR = BF_TRL + (long)NL * OUT_C * MID; // [256][128][32]
constexpr long BF_TLL = BF_TLR + (long)NL * OUT_C * MID; // [256][128][128]

typedef __bf16 bf16x8 __attribute__((ext_vector_type(8)));
typedef float  f32x4  __attribute__((ext_vector_type(4)));

__device__ inline unsigned short f2bf(float f) {
    unsigned int u = __float_as_uint(f);
    u = (u + 0x7fffu + ((u >> 16) & 1u)) >> 16;   // round-to-nearest-even
    return (unsigned short)u;
}

union BF8 { unsigned int u[4]; bf16x8 v; };

// ---------------------------------------------------------------------------
// K1: LayerNorm + MFMA projection. 96 blocks x 16 rows. (round-11 version)
// ---------------------------------------------------------------------------
__global__ __launch_bounds__(256) void ln_proj_kernel(
    const float* __restrict__ rec, const float* __restrict__ lig,
    const float* __restrict__ rg, const float* __restrict__ rb,
    const float* __restrict__ lg, const float* __restrict__ lb,
    const float* __restrict__ Wr, const float* __restrict__ br,
    const float* __restrict__ Wl, const float* __restrict__ bl,
    float* __restrict__ ws)
{
    __shared__ unsigned int xn4[16 * 128];     // 16 rows x 128 u32 (bf16 pairs), swizzled
    int bid = blockIdx.x;                      // 0..95; 0-31 rec, 32-95 lig
    int rowbase = bid * 16;
    bool isRec = (rowbase < NR);
    const float* X    = isRec ? rec + (long)rowbase * IN_C
                              : lig + (long)(rowbase - NR) * IN_C;
    const float* g    = isRec ? rg : lg;
    const float* bv   = isRec ? rb : lb;
    const float* W    = isRec ? Wr : Wl;
    const float* bias = isRec ? br : bl;

    int tid = threadIdx.x;
    // ---- LN phase: row rl = tid>>4, 16 lanes per row ----
    {
        int rl = tid >> 4, p = tid & 15;
        const float* xp = X + (long)rl * IN_C + p * 16;
        float4 xv[4];
        float s = 0.f, s2 = 0.f;
        #pragma unroll
        for (int q = 0; q < 4; ++q) {
            xv[q] = *(const float4*)(xp + q * 4);
            s  += xv[q].x + xv[q].y + xv[q].z + xv[q].w;
            s2 += xv[q].x*xv[q].x + xv[q].y*xv[q].y + xv[q].z*xv[q].z + xv[q].w*xv[q].w;
        }
        #pragma unroll
        for (int m = 1; m < 16; m <<= 1) {
            s  += __shfl_xor(s,  m, 64);
            s2 += __shfl_xor(s2, m, 64);
        }
        float mu = s * (1.f / IN_C);
        float var = s2 * (1.f / IN_C) - mu * mu;
        float rs = rsqrtf(var + 1e-5f);
        #pragma unroll
        for (int q = 0; q < 4; ++q) {
            int k0 = p * 16 + q * 4;
            float4 gv = *(const float4*)(g + k0);
            float4 bb = *(const float4*)(bv + k0);
            float n0 = (xv[q].x - mu) * rs * gv.x + bb.x;
            float n1 = (xv[q].y - mu) * rs * gv.y + bb.y;
            float n2 = (xv[q].z - mu) * rs * gv.z + bb.z;
            float n3 = (xv[q].w - mu) * rs * gv.w + bb.w;
            int idx  = rl * 128 + (k0 >> 1);             // even; %4 in {0,2}
            int sidx = idx ^ ((rl & 7) << 2);            // 16B-block XOR swizzle
            xn4[sidx]     = (unsigned)f2bf(n0) | ((unsigned)f2bf(n1) << 16);
            xn4[sidx + 1] = (unsigned)f2bf(n2) | ((unsigned)f2bf(n3) << 16);
        }
    }
    __syncthreads();

    // ---- MFMA projection: wave wv covers outs [wv*32, wv*32+32) ----
    int wv = tid >> 6, l = tid & 63;
    int lrow = l & 15, lk = l >> 4;
    int ob = wv * 32;

    f32x4 acc0 = *(const f32x4*)(bias + ob + lk * 4);        // outs ob+lk*4..+3
    f32x4 acc1 = *(const f32x4*)(bias + ob + 16 + lk * 4);

    for (int ks = 0; ks < 8; ++ks) {
        int idx = (lrow * 128 + ks * 16 + lk * 4) ^ ((lrow & 7) << 2);
        bf16x8 xf = *(const bf16x8*)&xn4[idx];               // B: xn row = lrow
        const float* w0 = W + (long)(ob + lrow) * IN_C + ks * 32 + lk * 8;
        const float* w1 = w0 + 16L * IN_C;
        float4 a0 = *(const float4*)w0, a1 = *(const float4*)(w0 + 4);
        float4 c0 = *(const float4*)w1, c1 = *(const float4*)(w1 + 4);
        BF8 wf0, wf1;
        wf0.u[0] = (unsigned)f2bf(a0.x) | ((unsigned)f2bf(a0.y) << 16);
        wf0.u[1] = (unsigned)f2bf(a0.z) | ((unsigned)f2bf(a0.w) << 16);
        wf0.u[2] = (unsigned)f2bf(a1.x) | ((unsigned)f2bf(a1.y) << 16);
        wf0.u[3] = (unsigned)f2bf(a1.z) | ((unsigned)f2bf(a1.w) << 16);
        wf1.u[0] = (unsigned)f2bf(c0.x) | ((unsigned)f2bf(c0.y) << 16);
        wf1.u[1] = (unsigned)f2bf(c0.z) | ((unsigned)f2bf(c0.w) << 16);
        wf1.u[2] = (unsigned)f2bf(c1.x) | ((unsigned)f2bf(c1.y) << 16);
        wf1.u[3] = (unsigned)f2bf(c1.z) | ((unsigned)f2bf(c1.w) << 16);
        acc0 = __builtin_amdgcn_mfma_f32_16x16x32_bf16(wf0.v, xf, acc0, 0, 0, 0);
        acc1 = __builtin_amdgcn_mfma_f32_16x16x32_bf16(wf1.v, xf, acc1, 0, 0, 0);
    }

    // ---- store: lane row = rowbase+lrow; tile t, reg r -> c = ob + t*16 + lk*4 + r
    unsigned short* wsb = (unsigned short*)ws;
    int prow = isRec ? (rowbase + lrow) : (rowbase - NR + lrow);
    long slice_stride = isRec ? (long)NR * MID : (long)M * NL * MID;
    float* P4 = isRec ? (ws + WS_PR4) : (ws + WS_PL4);
    #pragma unroll
    for (int t = 0; t < 2; ++t) {
        f32x4 acc = t ? acc1 : acc0;
        int xi = (ob >> 2) + t * 4 + lk;
        #pragma unroll
        for (int r = 0; r < 4; ++r) {
            float val = acc[r];
            P4[(long)r * slice_stride + (long)prow * MID + xi] = val;
            unsigned short hb = f2bf(val);
            if (isRec) {
                if (r == 0)      wsb[BF_LRR + (long)prow * 32 + xi] = hb;
                else if (r == 2) wsb[BF_LRL + (long)prow * 32 + xi] = hb;
                else if (r == 3) wsb[BF_LLR + (long)prow * 32 + xi] = hb;
            } else if (r == 2) { // l_li -> LLL[j][m*32+xi], prow = m*256+j
                wsb[BF_LLL + (long)(prow & 255) * 128 + (prow >> 8) * 32 + xi] = hb;
            }
        }
    }
}

// ---------------------------------------------------------------------------
// K3 (MFMA, uniform-block version): T[c][v] = W[c][y] . V[v][y], K=32.
// Every block = 64 c-rows x 256 v-rows (IDENTICAL work): rr 128 blocks,
// rl 64, lr 64, ll 256 -> 512 blocks = exactly 2/CU, zero dispatch tail
// (was 320 non-uniform blocks = 1.25/CU with 2:1 work imbalance).
// W chunks remain disjoint across blocks (W read once total - r11 lesson).
// ---------------------------------------------------------------------------
__global__ __launch_bounds__(256) void build_t_kernel(
    const float* __restrict__ Wrr, const float* __restrict__ Wrl,
    const float* __restrict__ Wlr, const float* __restrict__ Wll,
    float* __restrict__ ws)
{
    __shared__ unsigned int Vs[256 * 16];   // bf16 pairs, 16B-block XOR swizzle
    __shared__ unsigned int Wsh[64 * 16];
    unsigned short* wsb = (unsigned short*)ws;
    const float* V4 = ws + WS_PL4;          // [s][m][j][y]
    int bid = blockIdx.x;
    int tid = threadIdx.x;

    int mode, cblk, vc;
    const float* W;
    unsigned short* T;
    if (bid < 128)      { mode = 0; cblk = bid >> 1;  vc = bid & 1; W = Wrr; T = wsb + BF_TRR; }
    else if (bid < 192) { mode = 1; cblk = bid - 128; vc = 0;       W = Wrl; T = wsb + BF_TRL; }
    else if (bid < 256) { mode = 2; cblk = bid - 192; vc = 0;       W = Wlr; T = wsb + BF_TLR; }
    else                { mode = 3; int r = bid - 256; cblk = r >> 2; vc = r & 3;
                          W = Wll; T = wsb + BF_TLL; }

    // ---- stage V chunk (256 rows, f32 -> bf16 pairs, swizzled) ----
    {
        int row = tid >> 2, blk = tid & 3;       // wait: need 256 rows x 4 blks = 1024 iters / 256 thr = 4
        for (int it = 0; it < 4; ++it) {
            int f = tid + it * 256;
            row = f >> 2; blk = f & 3;
            int y0 = blk * 8;
            float vals[8];
            if (mode == 0) {
                const float* p = ws + WS_PR4 + (long)NR * MID + (long)(vc * 256 + row) * 32 + y0;  // r_rj
                #pragma unroll
                for (int i = 0; i < 8; ++i) vals[i] = p[i];
            } else if (mode == 3) {
                const float* p = V4 + 3L * M * NL * MID + (long)(vc * 256 + row) * 32 + y0;        // l_lj
                #pragma unroll
                for (int i = 0; i < 8; ++i) vals[i] = 0.25f * p[i];                // fold /m
            } else {
                int sl = (mode == 1) ? 1 : 0;                                      // l_rj / l_ri
                const float* p = V4 + (long)sl * M * NL * MID + (long)row * 32 + y0;
                #pragma unroll
                for (int i = 0; i < 8; ++i)
                    vals[i] = 0.25f * (p[i] + p[8192 + i] + p[16384 + i] + p[24576 + i]);
            }
            unsigned int* dst = &Vs[row * 16 + ((blk ^ (row & 3)) << 2)];
            #pragma unroll
            for (int q = 0; q < 4; ++q)
                dst[q] = (unsigned)f2bf(vals[2*q]) | ((unsigned)f2bf(vals[2*q+1]) << 16);
        }
    }
    // ---- stage W chunk: 64 rows x 32 y (one iter: tid>>2 = row, tid&3 = blk)
    {
        int row = tid >> 2, blk = tid & 3;
        const float* p = W + (long)(cblk * 64 + row) * 32 + blk * 8;
        float4 a = *(const float4*)p, b = *(const float4*)(p + 4);
        unsigned int* dst = &Wsh[row * 16 + ((blk ^ (row & 3)) << 2)];
        dst[0] = (unsigned)f2bf(a.x) | ((unsigned)f2bf(a.y) << 16);
        dst[1] = (unsigned)f2bf(a.z) | ((unsigned)f2bf(a.w) << 16);
        dst[2] = (unsigned)f2bf(b.x) | ((unsigned)f2bf(b.y) << 16);
        dst[3] = (unsigned)f2bf(b.z) | ((unsigned)f2bf(b.w) << 16);
    }
    __syncthreads();

    int wv = tid >> 6, l = tid & 63;
    int lrow = l & 15, lk = l >> 4;
    int wrow = wv * 16 + lrow;
    bf16x8 af = *(const bf16x8*)&Wsh[wrow * 16 + ((lk ^ (wrow & 3)) << 2)];
    int c0 = cblk * 64 + wv * 16 + lk * 4;

    for (int jt = 0; jt < 16; ++jt) {
        int vr = jt * 16 + lrow;
        bf16x8 bf = *(const bf16x8*)&Vs[vr * 16 + ((lk ^ (vr & 3)) << 2)];
        f32x4 acc = {0.f, 0.f, 0.f, 0.f};
        acc = __builtin_amdgcn_mfma_f32_16x16x32_bf16(af, bf, acc, 0, 0, 0);
        unsigned long long pk =
              (unsigned long long)f2bf(acc[0])
            | ((unsigned long long)f2bf(acc[1]) << 16)
            | ((unsigned long long)f2bf(acc[2]) << 32)
            | ((unsigned long long)f2bf(acc[3]) << 48);
        if (mode < 3) {
            *(unsigned long long*)(T + (long)(vc * 256 + vr) * 4096 + c0) = pk;
        } else {
            int vg = vc * 256 + vr;                  // m*256 + j
            int m = vg >> 8, j = vg & 255;
            *(unsigned long long*)(T + (long)j * 16384 + ((c0 >> 5) << 7) + m * 32 + (c0 & 31)) = pk;
        }
    }
}

// ---------------------------------------------------------------------------
// K4: MFMA epilogue, wave-per-j with inner i-chunk loop (round-13 proven best:
// 64-i tile, 4-j window, 2304 blocks = 9/CU; T re-reads are L2-absorbed).
// ---------------------------------------------------------------------------
template<int K>
__device__ inline void epi_wave(const unsigned short* __restrict__ L,
                                const unsigned short* __restrict__ T,
                                const float* __restrict__ bias,
                                float* __restrict__ obrow,
                                long istr, int i0, int lrow, int lk)
{
    constexpr int NK = K / 32;
    bf16x8 bl0[NK], bl1[NK];
    #pragma unroll
    for (int ks = 0; ks < NK; ++ks) {
        int kb = ks * 32 + lk * 8;
        bl0[ks] = *(const bf16x8*)(L + (long)(i0 + lrow) * K + kb);
        bl1[ks] = *(const bf16x8*)(L + (long)(i0 + 16 + lrow) * K + kb);
    }
    f32x4 acc[2][8];
    #pragma unroll
    for (int of = 0; of < 8; ++of) {
        f32x4 b4 = *(const f32x4*)(bias + of * 16 + lk * 4);
        acc[0][of] = b4; acc[1][of] = b4;
    }
    #pragma unroll
    for (int ks = 0; ks < NK; ++ks) {
        int kb = ks * 32 + lk * 8;
        #pragma unroll
        for (int of = 0; of < 8; ++of) {
            bf16x8 a = *(const bf16x8*)(T + (long)(of * 16 + lrow) * K + kb);
            acc[0][of] = __builtin_amdgcn_mfma_f32_16x16x32_bf16(a, bl0[ks], acc[0][of], 0, 0, 0);
            acc[1][of] = __builtin_amdgcn_mfma_f32_16x16x32_bf16(a, bl1[ks], acc[1][of], 0, 0, 0);
        }
    }
    float* obase = obrow + (long)lk * 4;
    #pragma unroll
    for (int fi = 0; fi < 2; ++fi) {
        long ibase = (long)(i0 + fi * 16 + lrow) * istr;
        #pragma unroll
        for (int of = 0; of < 8; ++of) {
            *(f32x4*)(obase + ibase + of * 16) = acc[fi][of];
        }
    }
}

__global__ __launch_bounds__(256) void epilogue_kernel(
    const float* __restrict__ ws, float* __restrict__ out,
    const float* __restrict__ brr, const float* __restrict__ brl,
    const float* __restrict__ blr, const float* __restrict__ bll)
{
    const unsigned short* wsb = (const unsigned short*)ws;
    int bid = blockIdx.x;
    int x = bid & 7;      // XCD (dispatch round-robin heuristic; perf-only)
    int r = bid >> 3;     // 0..287 within XCD

    const unsigned short *L, *Tq;
    const float* bias;
    float* ob;
    long istr, jstr;
    int j0, i0b, quadK;
    if (r < 128) {               // rr: 8 it x 16 jw (4 j each), j window 64/XCD
        int jw = r & 15, it = r >> 4;
        j0 = x * 64 + jw * 4; i0b = it * 64; quadK = 32;
        L = wsb + BF_LRR; Tq = wsb + BF_TRR; bias = brr;
        ob = out; jstr = 128; istr = ROW_STRIDE;
    } else if (r < 192) {        // rl
        int w = r - 128; int jw = w & 7, it = w >> 3;
        j0 = x * 32 + jw * 4; i0b = it * 64; quadK = 32;
        L = wsb + BF_LRL; Tq = wsb + BF_TRL; bias = brl;
        ob = out + (long)NR * OUT_C; jstr = 128; istr = ROW_STRIDE;
    } else if (r < 256) {        // lr: rows NR+j (lig), cols i (rec)
        int w = r - 192; int jw = w & 7, it = w >> 3;
        j0 = x * 32 + jw * 4; i0b = it * 64; quadK = 32;
        L = wsb + BF_LLR; Tq = wsb + BF_TLR; bias = blr;
        ob = out + (long)NR * ROW_STRIDE; jstr = ROW_STRIDE; istr = 128;
    } else {                     // ll: K=128
        int w = r - 256; int jw = w & 7, it = w >> 3;
        j0 = x * 32 + jw * 4; i0b = it * 64; quadK = 128;
        L = wsb + BF_LLL; Tq = wsb + BF_TLL; bias = bll;
        ob = out + (long)NR * ROW_STRIDE + (long)NR * OUT_C; jstr = 128; istr = ROW_STRIDE;
    }

    int tid = threadIdx.x;
    int wv = tid >> 6, l = tid & 63;
    int lrow = l & 15, lk = l >> 4;
    int j = j0 + wv;

    if (quadK == 32) {
        const unsigned short* T = Tq + (long)j * 4096;
        float* obj = ob + (long)j * jstr;
        #pragma unroll
        for (int ic = 0; ic < 2; ++ic)
            epi_wave<32>(L, T, bias, obj, istr, i0b + ic * 32, lrow, lk);
    } else {
        const unsigned short* T = Tq + (long)j * 16384;
        float* obj = ob + (long)j * jstr;
        #pragma unroll
        for (int ic = 0; ic < 2; ++ic)
            epi_wave<128>(L, T, bias, obj, istr, i0b + ic * 32, lrow, lk);
    }
}

extern "C" void kernel_launch(void* const* d_in, const int* in_sizes, int n_in,
                              void* d_out, int out_size, void* d_ws, size_t ws_size,
                              hipStream_t stream)
{
    (void)in_sizes; (void)n_in; (void)out_size; (void)ws_size;
    const float* rec = (const float*)d_in[0];
    const float* lig = (const float*)d_in[1];
    // d_in[2] = pw_rep: shape-only, never read (all 4 quadrants are overwritten)
    const float* rg  = (const float*)d_in[3];
    const float* rb  = (const float*)d_in[4];
    const float* lg  = (const float*)d_in[5];
    const float* lb  = (const float*)d_in[6];
    const float* Wr  = (const float*)d_in[7];
    const float* br  = (const float*)d_in[8];
    const float* Wl  = (const float*)d_in[9];
    const float* bl  = (const float*)d_in[10];
    const float* Wrr = (const float*)d_in[11];
    const float* brr = (const float*)d_in[12];
    const float* Wrl = (const float*)d_in[13];
    const float* brl = (const float*)d_in[14];
    const float* Wlr = (const float*)d_in[15];
    const float* blr = (const float*)d_in[16];
    const float* Wll = (const float*)d_in[17];
    const float* bll = (const float*)d_in[18];
    float* out = (float*)d_out;
    float* ws  = (float*)d_ws;

    hipLaunchKernelGGL(ln_proj_kernel, dim3(96), dim3(256), 0, stream,
                       rec, lig, rg, rb, lg, lb, Wr, br, Wl, bl, ws);
    hipLaunchKernelGGL(build_t_kernel, dim3(512), dim3(256), 0, stream,
                       Wrr, Wrl, Wlr, Wll, ws);
    hipLaunchKernelGGL(epilogue_kernel, dim3(2304), dim3(256), 0, stream,
                       ws, out, brr, brl, blr, bll);
}